// Round 1
// 2090.088 us; speedup vs baseline: 1.0077x; 1.0077x over previous
//
#include <hip/hip_runtime.h>
#include <math.h>

typedef short bf16x8 __attribute__((ext_vector_type(8)));
typedef float floatx4 __attribute__((ext_vector_type(4)));

__device__ __forceinline__ unsigned short f2bf(float f) {
    unsigned int u = __float_as_uint(f);
    u += 0x7fffu + ((u >> 16) & 1u);   // round-to-nearest-even
    return (unsigned short)(u >> 16);
}
__device__ __forceinline__ float bf2f(unsigned short u) {
    return __uint_as_float(((unsigned int)u) << 16);
}
// async global->LDS, 16B per lane; LDS dest = wave-uniform base + lane*16
__device__ __forceinline__ void async16(void* lds, const void* g) {
    __builtin_amdgcn_global_load_lds((const __attribute__((address_space(1))) unsigned int*)g,
                                     (__attribute__((address_space(3))) unsigned int*)lds,
                                     16, 0, 0);
}

// ---------------- weight convert: fp32 -> bf16, one layer's 4 tensors ----------------
// float4-unit segments: qkv 786432 | out 262144 | w1 2097152 | w2 1048576  (total 4194304)
__global__ __launch_bounds__(256) void conv_w(
        const float* __restrict__ qkv, const float* __restrict__ ow,
        const float* __restrict__ w1, const float* __restrict__ w2,
        unsigned short* __restrict__ dst) {
    size_t i = (size_t)blockIdx.x * 256 + threadIdx.x;
    const float* s; size_t off; unsigned short* d;
    if (i < 786432)       { s = qkv; off = i;           d = dst; }
    else if (i < 1048576) { s = ow;  off = i - 786432;  d = dst + 3145728; }
    else if (i < 3145728) { s = w1;  off = i - 1048576; d = dst + 4194304; }
    else                  { s = w2;  off = i - 3145728; d = dst + 12582912; }
    float4 v = ((const float4*)s)[off];
    ushort4 o;
    o.x = f2bf(v.x); o.y = f2bf(v.y); o.z = f2bf(v.z); o.w = f2bf(v.w);
    ((ushort4*)d)[off] = o;
}

// ---------------- RMSNorm: fp32 in -> bf16 out ----------------
__global__ __launch_bounds__(256) void rmsnorm_bf(
        const float* __restrict__ x, const float* __restrict__ w,
        unsigned short* __restrict__ out) {
    __shared__ float sred[4];
    int row = blockIdx.x;
    int t = threadIdx.x;
    float4 v = ((const float4*)(x + (size_t)row * 1024))[t];
    float ss = v.x*v.x + v.y*v.y + v.z*v.z + v.w*v.w;
#pragma unroll
    for (int m = 32; m >= 1; m >>= 1) ss += __shfl_xor(ss, m, 64);
    if ((t & 63) == 0) sred[t >> 6] = ss;
    __syncthreads();
    float tot = sred[0] + sred[1] + sred[2] + sred[3];
    float r = rsqrtf(tot * (1.0f / 1024.0f) + 1e-6f);
    float4 wv = ((const float4*)w)[t];
    ushort4 o;
    o.x = f2bf(v.x * r * wv.x); o.y = f2bf(v.y * r * wv.y);
    o.z = f2bf(v.z * r * wv.z); o.w = f2bf(v.w * r * wv.w);
    ((ushort4*)(out + (size_t)row * 1024))[t] = o;
}

// ---------------- GEMM: C[M,Nc] = A[M,Kd] * W[Nc,Kd]^T, bf16 in ----------------
// 128x128 tile, BK=32, 256 thr = 4 waves (2x2 of 64x64), m97 structure.
// OUTMODE 0: store bf16. OUTMODE 1: fp32 atomicAdd (split-K over blockIdx.z; residual free).
template<int OUTMODE>
__global__ __launch_bounds__(256) void gemm_bf(
        const unsigned short* __restrict__ A, const unsigned short* __restrict__ W,
        void* __restrict__ Cout, int Ncols, int Kd) {
    __shared__ __align__(16) unsigned short As[128 * 32];
    __shared__ __align__(16) unsigned short Bs[128 * 32];
    int t = threadIdx.x;
    int wave = t >> 6, lane = t & 63;
    int wm = wave >> 1, wn = wave & 1;
    int lrow = lane & 15, quad = lane >> 4;
    int bmBase = blockIdx.y * 128, bnBase = blockIdx.x * 128;
    int kslice = Kd / gridDim.z;
    int kBeg = blockIdx.z * kslice, kEnd = kBeg + kslice;

    int sub = lane >> 2;           // row within chunk (16 rows of 64B)
    int colb = (lane & 3) * 8;     // elem col within 32
    int c0 = wave, c1 = wave + 4;  // this wave's chunks (of 8 per tile)

    floatx4 acc[4][4] = {};

    for (int k0 = kBeg; k0 < kEnd; k0 += 32) {
        async16(&As[c0 * 512 + lane * 8], A + (size_t)(bmBase + c0 * 16 + sub) * Kd + k0 + colb);
        async16(&As[c1 * 512 + lane * 8], A + (size_t)(bmBase + c1 * 16 + sub) * Kd + k0 + colb);
        async16(&Bs[c0 * 512 + lane * 8], W + (size_t)(bnBase + c0 * 16 + sub) * Kd + k0 + colb);
        async16(&Bs[c1 * 512 + lane * 8], W + (size_t)(bnBase + c1 * 16 + sub) * Kd + k0 + colb);
        __syncthreads();
        bf16x8 af[4], bfr[4];
#pragma unroll
        for (int im = 0; im < 4; im++)
            af[im] = *(const bf16x8*)&As[(wm * 64 + im * 16 + lrow) * 32 + quad * 8];
#pragma unroll
        for (int in = 0; in < 4; in++)
            bfr[in] = *(const bf16x8*)&Bs[(wn * 64 + in * 16 + lrow) * 32 + quad * 8];
#pragma unroll
        for (int im = 0; im < 4; im++)
#pragma unroll
            for (int in = 0; in < 4; in++)
                acc[im][in] = __builtin_amdgcn_mfma_f32_16x16x32_bf16(af[im], bfr[in], acc[im][in], 0, 0, 0);
        __syncthreads();
    }

#pragma unroll
    for (int im = 0; im < 4; im++) {
        int gr0 = bmBase + wm * 64 + im * 16 + quad * 4;
#pragma unroll
        for (int in = 0; in < 4; in++) {
            int gc = bnBase + wn * 64 + in * 16 + lrow;
#pragma unroll
            for (int r2 = 0; r2 < 4; r2++) {
                size_t off = (size_t)(gr0 + r2) * Ncols + gc;
                if (OUTMODE == 0) ((unsigned short*)Cout)[off] = f2bf(acc[im][in][r2]);
                else              atomicAdd((float*)Cout + off, acc[im][in][r2]);
            }
        }
    }
}

// ---------------- GEMM 256x256: BK=64, 512 thr = 8 waves (2Mx4N), dbuf LDS ----------------
// T2 granule-XOR swizzle (pre-swizzled global source + swizzled ds_read, rule 21),
// T3 4-phase interleave (one C-quadrant x K=64 per phase, 1 half-tile staged per phase),
// T4 counted vmcnt(2) at iter top (never 0 in steady state), T5 setprio around MFMA.
// Sync derivation: reads of buf[b] in iter t complete before t's ph3-trailing barrier
// (lgkmcnt before MFMA use); first write into buf[b] is issued in iter t+1 after that
// barrier => no write/read race. B_ready barrier follows each wave's own vmcnt => all
// waves' DMA writes landed before any ds_read of the tile.
// OUTMODE 0: store bf16. OUTMODE 1: fp32 atomicAdd (split-K over blockIdx.z).
template<int OUTMODE>
__global__ __launch_bounds__(512, 2) void gemm256(
        const unsigned short* __restrict__ A, const unsigned short* __restrict__ W,
        void* __restrict__ Cout, int Ncols, int Kd) {
    __shared__ __align__(16) unsigned short S[2][4][8192];  // [buf][Alo,Ahi,Blo,Bhi][128*64]
    const int t = threadIdx.x;
    const int wave = t >> 6, lane = t & 63;
    const int wm = wave >> 2, wn = wave & 3;          // 2 x 4 wave grid
    const int lrow = lane & 15, quad = lane >> 4;
    const int sub8 = lane >> 3;
    const int lgoff = ((lane & 7) ^ sub8) * 8;        // staging: logical granule for phys slot
    const int pg0 = ((quad)     ^ (lrow & 7)) * 8;    // ds_read: phys granule, ks=0
    const int pg1 = ((quad + 4) ^ (lrow & 7)) * 8;    // ks=1
    const int brow = (wn & 1) * 64;

    const int tileM = blockIdx.y * 256, tileN = blockIdx.x * 256;
    const int kslice = Kd / gridDim.z;
    const int kBeg = blockIdx.z * kslice;
    const int nt = kslice >> 6;

    const size_t thrOff = (size_t)(wave * 16 + sub8) * Kd + lgoff;
    const size_t c8 = (size_t)8 * Kd;                 // chunk1 = +8 rows
    const unsigned short* p0 = A + (size_t)tileM * Kd + kBeg + thrOff;          // A rows 0..127
    const unsigned short* p1 = p0 + (size_t)128 * Kd;                           // A rows 128..255
    const unsigned short* p2 = W + (size_t)tileN * Kd + kBeg + thrOff;          // B cols 0..127
    const unsigned short* p3 = p2 + (size_t)128 * Kd;                           // B cols 128..255

    const int ldst0 = wave * 1024 + lane * 8;         // chunk 2w   (ushort idx)
    const int ldst1 = ldst0 + 512;                    // chunk 2w+1

    floatx4 acc[8][4] = {};

    // prologue: stage K-tile 0 into buf 0 (8 async16 per thread)
    async16(&S[0][0][ldst0], p0); async16(&S[0][0][ldst1], p0 + c8);
    async16(&S[0][1][ldst0], p1); async16(&S[0][1][ldst1], p1 + c8);
    async16(&S[0][2][ldst0], p2); async16(&S[0][2][ldst1], p2 + c8);
    async16(&S[0][3][ldst0], p3); async16(&S[0][3][ldst1], p3 + c8);

    for (int tk = 0; tk < nt; ++tk) {
        const int cur = tk & 1, nxt = cur ^ 1;
        const size_t ko = (size_t)(tk + 1) * 64;
        const bool pf = (tk + 1 < nt);
        const unsigned short* Sa = &S[cur][wm][0];
        const unsigned short* Sb = &S[cur][2 + (wn >> 1)][0];

        if (pf) {   // issue next-tile A-lo, then drain the 8 loads of tile tk (keep 2 in flight)
            async16(&S[nxt][0][ldst0], p0 + ko);
            async16(&S[nxt][0][ldst1], p0 + ko + c8);
            asm volatile("s_waitcnt vmcnt(2)" ::: "memory");
        } else {
            asm volatile("s_waitcnt vmcnt(0)" ::: "memory");
        }
        __builtin_amdgcn_s_barrier();   // B_ready: tile tk fully landed for all waves

        bf16x8 afr[4][2], bfr[4][2];
        // ---- phase 1: read A(mh0) + B(n0,n1); stage A-hi; MFMA quad(m0-3, n0-1) ----
#pragma unroll
        for (int m = 0; m < 4; ++m) {
            const unsigned short* r = &Sa[(m * 16 + lrow) * 64];
            afr[m][0] = *(const bf16x8*)&r[pg0];
            afr[m][1] = *(const bf16x8*)&r[pg1];
        }
#pragma unroll
        for (int n = 0; n < 2; ++n) {
            const unsigned short* r = &Sb[(brow + n * 16 + lrow) * 64];
            bfr[n][0] = *(const bf16x8*)&r[pg0];
            bfr[n][1] = *(const bf16x8*)&r[pg1];
        }
        if (pf) { async16(&S[nxt][1][ldst0], p1 + ko); async16(&S[nxt][1][ldst1], p1 + ko + c8); }
        __builtin_amdgcn_s_barrier();
        asm volatile("s_waitcnt lgkmcnt(0)" ::: "memory");
        __builtin_amdgcn_sched_barrier(0);
        __builtin_amdgcn_s_setprio(1);
#pragma unroll
        for (int m = 0; m < 4; ++m)
#pragma unroll
            for (int n = 0; n < 2; ++n) {
                acc[m][n] = __builtin_amdgcn_mfma_f32_16x16x32_bf16(afr[m][0], bfr[n][0], acc[m][n], 0, 0, 0);
                acc[m][n] = __builtin_amdgcn_mfma_f32_16x16x32_bf16(afr[m][1], bfr[n][1], acc[m][n], 0, 0, 0);
            }
        __builtin_amdgcn_s_setprio(0);
        __builtin_amdgcn_s_barrier();

        // ---- phase 2: read B(n2,n3); stage B-lo; MFMA quad(m0-3, n2-3) ----
#pragma unroll
        for (int n = 2; n < 4; ++n) {
            const unsigned short* r = &Sb[(brow + n * 16 + lrow) * 64];
            bfr[n][0] = *(const bf16x8*)&r[pg0];
            bfr[n][1] = *(const bf16x8*)&r[pg1];
        }
        if (pf) { async16(&S[nxt][2][ldst0], p2 + ko); async16(&S[nxt][2][ldst1], p2 + ko + c8); }
        __builtin_amdgcn_s_barrier();
        asm volatile("s_waitcnt lgkmcnt(0)" ::: "memory");
        __builtin_amdgcn_sched_barrier(0);
        __builtin_amdgcn_s_setprio(1);
#pragma unroll
        for (int m = 0; m < 4; ++m)
#pragma unroll
            for (int n = 2; n < 4; ++n) {
                acc[m][n] = __builtin_amdgcn_mfma_f32_16x16x32_bf16(afr[m][0], bfr[n][0], acc[m][n], 0, 0, 0);
                acc[m][n] = __builtin_amdgcn_mfma_f32_16x16x32_bf16(afr[m][1], bfr[n][1], acc[m][n], 0, 0, 0);
            }
        __builtin_amdgcn_s_setprio(0);
        __builtin_amdgcn_s_barrier();

        // ---- phase 3: read A(mh1) (overwrite afr); stage B-hi; MFMA quad(m4-7, n2-3) ----
#pragma unroll
        for (int m = 0; m < 4; ++m) {
            const unsigned short* r = &Sa[((m + 4) * 16 + lrow) * 64];
            afr[m][0] = *(const bf16x8*)&r[pg0];
            afr[m][1] = *(const bf16x8*)&r[pg1];
        }
        if (pf) { async16(&S[nxt][3][ldst0], p3 + ko); async16(&S[nxt][3][ldst1], p3 + ko + c8); }
        __builtin_amdgcn_s_barrier();
        asm volatile("s_waitcnt lgkmcnt(0)" ::: "memory");
        __builtin_amdgcn_sched_barrier(0);
        __builtin_amdgcn_s_setprio(1);
#pragma unroll
        for (int m = 0; m < 4; ++m)
#pragma unroll
            for (int n = 2; n < 4; ++n) {
                acc[m + 4][n] = __builtin_amdgcn_mfma_f32_16x16x32_bf16(afr[m][0], bfr[n][0], acc[m + 4][n], 0, 0, 0);
                acc[m + 4][n] = __builtin_amdgcn_mfma_f32_16x16x32_bf16(afr[m][1], bfr[n][1], acc[m + 4][n], 0, 0, 0);
            }
        __builtin_amdgcn_s_setprio(0);
        __builtin_amdgcn_s_barrier();   // after this: all LDS reads of buf[cur] complete chip-wide

        // ---- phase 4: registers only; MFMA quad(m4-7, n0-1) ----
        __builtin_amdgcn_s_setprio(1);
#pragma unroll
        for (int m = 0; m < 4; ++m)
#pragma unroll
            for (int n = 0; n < 2; ++n) {
                acc[m + 4][n] = __builtin_amdgcn_mfma_f32_16x16x32_bf16(afr[m][0], bfr[n][0], acc[m + 4][n], 0, 0, 0);
                acc[m + 4][n] = __builtin_amdgcn_mfma_f32_16x16x32_bf16(afr[m][1], bfr[n][1], acc[m + 4][n], 0, 0, 0);
            }
        __builtin_amdgcn_s_setprio(0);
    }

    // epilogue: C/D layout col=lane&15, row=quad*4+reg
#pragma unroll
    for (int m = 0; m < 8; ++m) {
        int gr0 = tileM + wm * 128 + m * 16 + quad * 4;
#pragma unroll
        for (int n = 0; n < 4; ++n) {
            int gc = tileN + wn * 64 + n * 16 + lrow;
#pragma unroll
            for (int r2 = 0; r2 < 4; ++r2) {
                size_t off = (size_t)(gr0 + r2) * Ncols + gc;
                if (OUTMODE == 0) ((unsigned short*)Cout)[off] = f2bf(acc[m][n][r2]);
                else              atomicAdd((float*)Cout + off, acc[m][n][r2]);
            }
        }
    }
}

// ---------------- RoPE + split qkv (bf16) -> q, k, vT (bf16) ----------------
__global__ __launch_bounds__(512) void rope_bf(
        const unsigned short* __restrict__ qkv, unsigned short* __restrict__ q,
        unsigned short* __restrict__ k, unsigned short* __restrict__ vt) {
    int n = blockIdx.x;
    int t = threadIdx.x;
    int h = t >> 5, j = t & 31;
    float inv = powf(10000.0f, -(float)j * (1.0f / 32.0f));
    float ang = (float)n * inv;
    float s = sinf(ang), c = cosf(ang);
    const unsigned short* base = qkv + (size_t)n * 3072;
    int o1 = h * 64 + j, o2 = o1 + 32;
    float q1 = bf2f(base[o1]),        q2 = bf2f(base[o2]);
    float k1 = bf2f(base[1024 + o1]), k2 = bf2f(base[1024 + o2]);
    q[(size_t)n * 1024 + o1] = f2bf(q1 * c - q2 * s);
    q[(size_t)n * 1024 + o2] = f2bf(q2 * c + q1 * s);
    k[(size_t)n * 1024 + o1] = f2bf(k1 * c - k2 * s);
    k[(size_t)n * 1024 + o2] = f2bf(k2 * c + k1 * s);
    vt[(size_t)o1 * 2048 + n] = base[2048 + o1];
    vt[(size_t)o2 * 2048 + n] = base[2048 + o2];
}

// ---------------- Flash attention (causal), bf16 in, bf16 out ----------------
// grid (32 qblocks, 16 heads), 256 thr = 4 waves; wave w owns q rows w*16..+15
__global__ __launch_bounds__(256) void attn_bf(
        const unsigned short* __restrict__ q, const unsigned short* __restrict__ kbuf,
        const unsigned short* __restrict__ vt, unsigned short* __restrict__ attn) {
    __shared__ __align__(16) unsigned short Qs[64 * 64];
    __shared__ __align__(16) unsigned short Ks[64 * 64];
    __shared__ __align__(16) unsigned short Vs[64 * 64];   // [dim][key]
    __shared__ __align__(16) unsigned short Ps[4 * 16 * 64];
    int qb = blockIdx.x;
    int h  = blockIdx.y;
    int t = threadIdx.x;
    int wave = t >> 6, lane = t & 63;
    int lrow = lane & 15, quad = lane >> 4;
    int sub8 = lane >> 3;           // row within 8-row chunk
    int col8 = (lane & 7) * 8;      // elem col within 64
    int c0 = wave, c1 = wave + 4;

    // stage Q (64 rows x 64 dims): 8 chunks of 1KB
    async16(&Qs[c0 * 512 + lane * 8], q + (size_t)(qb * 64 + c0 * 8 + sub8) * 1024 + h * 64 + col8);
    async16(&Qs[c1 * 512 + lane * 8], q + (size_t)(qb * 64 + c1 * 8 + sub8) * 1024 + h * 64 + col8);

    floatx4 oacc[4] = {};
    float mrow[4], lsum[4];
#pragma unroll
    for (int r2 = 0; r2 < 4; r2++) { mrow[r2] = -INFINITY; lsum[r2] = 0.0f; }

    for (int kt = 0; kt <= qb; ++kt) {
        __syncthreads();  // prior iter's LDS reads done (also drains Q asyncs on iter 0)
        async16(&Ks[c0 * 512 + lane * 8], kbuf + (size_t)(kt * 64 + c0 * 8 + sub8) * 1024 + h * 64 + col8);
        async16(&Ks[c1 * 512 + lane * 8], kbuf + (size_t)(kt * 64 + c1 * 8 + sub8) * 1024 + h * 64 + col8);
        async16(&Vs[c0 * 512 + lane * 8], vt + (size_t)(h * 64 + c0 * 8 + sub8) * 2048 + kt * 64 + col8);
        async16(&Vs[c1 * 512 + lane * 8], vt + (size_t)(h * 64 + c1 * 8 + sub8) * 2048 + kt * 64 + col8);
        __syncthreads();

        // S = Q K^T (wave's 16 q rows x 64 keys)
        floatx4 sacc[4] = {};
#pragma unroll
        for (int kk = 0; kk < 64; kk += 32) {
            bf16x8 aq = *(const bf16x8*)&Qs[(wave * 16 + lrow) * 64 + kk + quad * 8];
#pragma unroll
            for (int jn = 0; jn < 4; jn++) {
                bf16x8 bk = *(const bf16x8*)&Ks[(jn * 16 + lrow) * 64 + kk + quad * 8];
                sacc[jn] = __builtin_amdgcn_mfma_f32_16x16x32_bf16(aq, bk, sacc[jn], 0, 0, 0);
            }
        }

        // online softmax per q-row (row = quad*4 + r2, 16 cols per 16-lane group)
#pragma unroll
        for (int r2 = 0; r2 < 4; r2++) {
            int qg = qb * 64 + wave * 16 + quad * 4 + r2;
            float sv[4];
            float rm = -INFINITY;
#pragma unroll
            for (int jn = 0; jn < 4; jn++) {
                float xv = sacc[jn][r2] * 0.125f;
                int kg = kt * 64 + jn * 16 + lrow;
                if (kg > qg) xv = -INFINITY;
                sv[jn] = xv;
                rm = fmaxf(rm, xv);
            }
#pragma unroll
            for (int m = 8; m >= 1; m >>= 1) rm = fmaxf(rm, __shfl_xor(rm, m, 64));
            float mnew = fmaxf(mrow[r2], rm);
            float alpha = __expf(mrow[r2] - mnew);
            float rs = 0.0f;
#pragma unroll
            for (int jn = 0; jn < 4; jn++) {
                float p = __expf(sv[jn] - mnew);
                rs += p;
                Ps[wave * 1024 + (quad * 4 + r2) * 64 + jn * 16 + lrow] = f2bf(p);
            }
#pragma unroll
            for (int m = 8; m >= 1; m >>= 1) rs += __shfl_xor(rs, m, 64);
            lsum[r2] = lsum[r2] * alpha + rs;
            mrow[r2] = mnew;
#pragma unroll
            for (int jd = 0; jd < 4; jd++) oacc[jd][r2] *= alpha;
        }
        __syncthreads();  // Ps visible

        // O += P V
#pragma unroll
        for (int kk = 0; kk < 64; kk += 32) {
            bf16x8 ap = *(const bf16x8*)&Ps[wave * 1024 + lrow * 64 + kk + quad * 8];
#pragma unroll
            for (int jd = 0; jd < 4; jd++) {
                bf16x8 bv = *(const bf16x8*)&Vs[(jd * 16 + lrow) * 64 + kk + quad * 8];
                oacc[jd] = __builtin_amdgcn_mfma_f32_16x16x32_bf16(ap, bv, oacc[jd], 0, 0, 0);
            }
        }
    }

#pragma unroll
    for (int r2 = 0; r2 < 4; r2++) {
        int qg = qb * 64 + wave * 16 + quad * 4 + r2;
        float invl = 1.0f / lsum[r2];
#pragma unroll
        for (int jd = 0; jd < 4; jd++)
            attn[(size_t)qg * 1024 + h * 64 + jd * 16 + lrow] = f2bf(oacc[jd][r2] * invl);
    }
}

// ---------------- SiLU gate: a[2048,8192] bf16 -> g[2048,4096] bf16 ----------------
__global__ __launch_bounds__(256) void silu_bf(
        const unsigned short* __restrict__ a, unsigned short* __restrict__ g) {
    int i = blockIdx.x * 256 + threadIdx.x;   // ushort4 unit over 2048*4096
    int n = i >> 10, c = (i & 1023) << 2;
    ushort4 a1 = *(const ushort4*)(a + (size_t)n * 8192 + c);
    ushort4 a2 = *(const ushort4*)(a + (size_t)n * 8192 + 4096 + c);
    float x0 = bf2f(a1.x), x1 = bf2f(a1.y), x2 = bf2f(a1.z), x3 = bf2f(a1.w);
    ushort4 o;
    o.x = f2bf(x0 / (1.0f + __expf(-x0)) * bf2f(a2.x));
    o.y = f2bf(x1 / (1.0f + __expf(-x1)) * bf2f(a2.y));
    o.z = f2bf(x2 / (1.0f + __expf(-x2)) * bf2f(a2.z));
    o.w = f2bf(x3 / (1.0f + __expf(-x3)) * bf2f(a2.w));
    *(ushort4*)(g + (size_t)n * 4096 + c) = o;
}

// ---------------- launch ----------------
extern "C" void kernel_launch(void* const* d_in, const int* in_sizes, int n_in,
                              void* d_out, int out_size, void* d_ws, size_t ws_size,
                              hipStream_t stream) {
    const float* x     = (const float*)d_in[0];
    const float* qkv_w = (const float*)d_in[1];
    const float* out_w = (const float*)d_in[2];
    const float* w1    = (const float*)d_in[3];
    const float* w2    = (const float*)d_in[4];
    const float* n1    = (const float*)d_in[5];
    const float* n2    = (const float*)d_in[6];

    char* ws = (char*)d_ws;
    float*          xbuf  = (float*)ws;                                   // 8,388,608 B
    unsigned short* hbuf  = (unsigned short*)(ws + 8388608);              // 4,194,304 B
    unsigned short* wslot = (unsigned short*)(ws + 12582912);             // 33,554,432 B
    char*           arena = ws + 46137344;                                // 50,331,648 B
    unsigned short* qkvb  = (unsigned short*)arena;                       // 12,582,912 B
    unsigned short* qb_   = (unsigned short*)(arena + 12582912);          // 4,194,304 B
    unsigned short* kb_   = (unsigned short*)(arena + 16777216);
    unsigned short* vtb   = (unsigned short*)(arena + 20971520);
    unsigned short* attnb = (unsigned short*)(arena + 25165824);
    unsigned short* abuf  = (unsigned short*)arena;                       // 33,554,432 B (attn bufs dead)
    unsigned short* gbuf  = (unsigned short*)(arena + 33554432);          // 16,777,216 B

    unsigned short* qkvw_bf = wslot;
    unsigned short* outw_bf = wslot + 3145728;
    unsigned short* w1_bf   = wslot + 4194304;
    unsigned short* w2_bf   = wslot + 12582912;

    hipMemcpyAsync(xbuf, x, (size_t)2048 * 1024 * 4, hipMemcpyDeviceToDevice, stream);

    for (int i = 0; i < 6; i++) {
        conv_w<<<16384, 256, 0, stream>>>(qkv_w + (size_t)i * 3145728, out_w + (size_t)i * 1048576,
                                          w1 + (size_t)i * 8388608, w2 + (size_t)i * 4194304, wslot);
        rmsnorm_bf<<<2048, 256, 0, stream>>>(xbuf, n1 + (size_t)i * 1024, hbuf);
        gemm_bf<0><<<dim3(24, 16, 1), 256, 0, stream>>>(hbuf, qkvw_bf, qkvb, 3072, 1024);
        rope_bf<<<2048, 512, 0, stream>>>(qkvb, qb_, kb_, vtb);
        attn_bf<<<dim3(32, 16), 256, 0, stream>>>(qb_, kb_, vtb, attnb);
        gemm_bf<1><<<dim3(8, 16, 2), 256, 0, stream>>>(attnb, outw_bf, xbuf, 1024, 1024);
        rmsnorm_bf<<<2048, 256, 0, stream>>>(xbuf, n2 + (size_t)i * 1024, hbuf);
        gemm256<0><<<dim3(32, 8, 1), 512, 0, stream>>>(hbuf, w1_bf, abuf, 8192, 1024);
        silu_bf<<<8192, 256, 0, stream>>>(abuf, gbuf);
        gemm256<1><<<dim3(4, 8, 8), 512, 0, stream>>>(gbuf, w2_bf, xbuf, 1024, 4096);
    }

    hipMemcpyAsync(d_out, xbuf, (size_t)2048 * 1024 * 4, hipMemcpyDeviceToDevice, stream);
}

// Round 2
// 2079.233 us; speedup vs baseline: 1.0129x; 1.0052x over previous
//
#include <hip/hip_runtime.h>
#include <math.h>

typedef short bf16x8 __attribute__((ext_vector_type(8)));
typedef float floatx4 __attribute__((ext_vector_type(4)));

__device__ __forceinline__ unsigned short f2bf(float f) {
    unsigned int u = __float_as_uint(f);
    u += 0x7fffu + ((u >> 16) & 1u);   // round-to-nearest-even
    return (unsigned short)(u >> 16);
}
__device__ __forceinline__ float bf2f(unsigned short u) {
    return __uint_as_float(((unsigned int)u) << 16);
}
// async global->LDS, 16B per lane; LDS dest = wave-uniform base + lane*16
__device__ __forceinline__ void async16(void* lds, const void* g) {
    __builtin_amdgcn_global_load_lds((const __attribute__((address_space(1))) unsigned int*)g,
                                     (__attribute__((address_space(3))) unsigned int*)lds,
                                     16, 0, 0);
}

// ---------------- weight convert: fp32 -> bf16, one layer's 4 tensors ----------------
// float4-unit segments: qkv 786432 | out 262144 | w1 2097152 | w2 1048576  (total 4194304)
__global__ __launch_bounds__(256) void conv_w(
        const float* __restrict__ qkv, const float* __restrict__ ow,
        const float* __restrict__ w1, const float* __restrict__ w2,
        unsigned short* __restrict__ dst) {
    size_t i = (size_t)blockIdx.x * 256 + threadIdx.x;
    const float* s; size_t off; unsigned short* d;
    if (i < 786432)       { s = qkv; off = i;           d = dst; }
    else if (i < 1048576) { s = ow;  off = i - 786432;  d = dst + 3145728; }
    else if (i < 3145728) { s = w1;  off = i - 1048576; d = dst + 4194304; }
    else                  { s = w2;  off = i - 3145728; d = dst + 12582912; }
    float4 v = ((const float4*)s)[off];
    ushort4 o;
    o.x = f2bf(v.x); o.y = f2bf(v.y); o.z = f2bf(v.z); o.w = f2bf(v.w);
    ((ushort4*)d)[off] = o;
}

// ---------------- RMSNorm: fp32 in -> bf16 out ----------------
__global__ __launch_bounds__(256) void rmsnorm_bf(
        const float* __restrict__ x, const float* __restrict__ w,
        unsigned short* __restrict__ out) {
    __shared__ float sred[4];
    int row = blockIdx.x;
    int t = threadIdx.x;
    float4 v = ((const float4*)(x + (size_t)row * 1024))[t];
    float ss = v.x*v.x + v.y*v.y + v.z*v.z + v.w*v.w;
#pragma unroll
    for (int m = 32; m >= 1; m >>= 1) ss += __shfl_xor(ss, m, 64);
    if ((t & 63) == 0) sred[t >> 6] = ss;
    __syncthreads();
    float tot = sred[0] + sred[1] + sred[2] + sred[3];
    float r = rsqrtf(tot * (1.0f / 1024.0f) + 1e-6f);
    float4 wv = ((const float4*)w)[t];
    ushort4 o;
    o.x = f2bf(v.x * r * wv.x); o.y = f2bf(v.y * r * wv.y);
    o.z = f2bf(v.z * r * wv.z); o.w = f2bf(v.w * r * wv.w);
    ((ushort4*)(out + (size_t)row * 1024))[t] = o;
}

// ---------------- GEMM: C[M,Nc] = A[M,Kd] * W[Nc,Kd]^T, bf16 in ----------------
// 128x128 tile, BK=32, 256 thr = 4 waves (2x2 of 64x64), m97 structure.
// OUTMODE 0: store bf16. OUTMODE 1: fp32 atomicAdd (split-K over blockIdx.z; residual free).
template<int OUTMODE>
__global__ __launch_bounds__(256) void gemm_bf(
        const unsigned short* __restrict__ A, const unsigned short* __restrict__ W,
        void* __restrict__ Cout, int Ncols, int Kd) {
    __shared__ __align__(16) unsigned short As[128 * 32];
    __shared__ __align__(16) unsigned short Bs[128 * 32];
    int t = threadIdx.x;
    int wave = t >> 6, lane = t & 63;
    int wm = wave >> 1, wn = wave & 1;
    int lrow = lane & 15, quad = lane >> 4;
    int bmBase = blockIdx.y * 128, bnBase = blockIdx.x * 128;
    int kslice = Kd / gridDim.z;
    int kBeg = blockIdx.z * kslice, kEnd = kBeg + kslice;

    int sub = lane >> 2;           // row within chunk (16 rows of 64B)
    int colb = (lane & 3) * 8;     // elem col within 32
    int c0 = wave, c1 = wave + 4;  // this wave's chunks (of 8 per tile)

    floatx4 acc[4][4] = {};

    for (int k0 = kBeg; k0 < kEnd; k0 += 32) {
        async16(&As[c0 * 512 + lane * 8], A + (size_t)(bmBase + c0 * 16 + sub) * Kd + k0 + colb);
        async16(&As[c1 * 512 + lane * 8], A + (size_t)(bmBase + c1 * 16 + sub) * Kd + k0 + colb);
        async16(&Bs[c0 * 512 + lane * 8], W + (size_t)(bnBase + c0 * 16 + sub) * Kd + k0 + colb);
        async16(&Bs[c1 * 512 + lane * 8], W + (size_t)(bnBase + c1 * 16 + sub) * Kd + k0 + colb);
        __syncthreads();
        bf16x8 af[4], bfr[4];
#pragma unroll
        for (int im = 0; im < 4; im++)
            af[im] = *(const bf16x8*)&As[(wm * 64 + im * 16 + lrow) * 32 + quad * 8];
#pragma unroll
        for (int in = 0; in < 4; in++)
            bfr[in] = *(const bf16x8*)&Bs[(wn * 64 + in * 16 + lrow) * 32 + quad * 8];
#pragma unroll
        for (int im = 0; im < 4; im++)
#pragma unroll
            for (int in = 0; in < 4; in++)
                acc[im][in] = __builtin_amdgcn_mfma_f32_16x16x32_bf16(af[im], bfr[in], acc[im][in], 0, 0, 0);
        __syncthreads();
    }

#pragma unroll
    for (int im = 0; im < 4; im++) {
        int gr0 = bmBase + wm * 64 + im * 16 + quad * 4;
#pragma unroll
        for (int in = 0; in < 4; in++) {
            int gc = bnBase + wn * 64 + in * 16 + lrow;
#pragma unroll
            for (int r2 = 0; r2 < 4; r2++) {
                size_t off = (size_t)(gr0 + r2) * Ncols + gc;
                if (OUTMODE == 0) ((unsigned short*)Cout)[off] = f2bf(acc[im][in][r2]);
                else              atomicAdd((float*)Cout + off, acc[im][in][r2]);
            }
        }
    }
}

// ---------------- GEMM 256x256: BK=64, 512 thr = 8 waves (2Mx4N), dbuf LDS ----------------
// T2 granule-XOR swizzle (pre-swizzled global source + swizzled ds_read, rule 21),
// T3 4-phase interleave, T4 counted vmcnt (never 0 in steady state), T5 setprio.
// R2 change vs R1: no sched_barrier(0)/lgkmcnt(0) pinning (m141: order-pinning -> 510 TF);
// compiler emits counted lgkmcnt for ds_read->MFMA deps. Barriers are asm w/ "memory"
// clobber = HW barrier + compiler fence at phase boundaries (no unsound load motion).
// Staging is front-loaded: A-halves of t+1 at tile top, B-halves in phase 1, so every
// prefetch has >1 full tile of compute (~2000 clk) to cover HBM latency; steady-state
// wait is vmcnt(4) (t's 8 loads drained, t+1's 4 A-loads stay in flight).
// Write/read hazard proof: reads of buf b complete before their consuming MFMA
// (compiler lgkm wait) which precedes ph3's trailing barrier; first DMA write into
// buf b is issued after that barrier in the NEXT iteration => no race.
template<int OUTMODE>
__global__ __launch_bounds__(512, 2) void gemm256(
        const unsigned short* __restrict__ A, const unsigned short* __restrict__ W,
        void* __restrict__ Cout, int Ncols, int Kd) {
    __shared__ __align__(16) unsigned short S[2][4][8192];  // [buf][Alo,Ahi,Blo,Bhi][128*64]
    const int t = threadIdx.x;
    const int wave = t >> 6, lane = t & 63;
    const int wm = wave >> 2, wn = wave & 3;          // 2 x 4 wave grid
    const int lrow = lane & 15, quad = lane >> 4;
    const int sub8 = lane >> 3;
    const int lgoff = ((lane & 7) ^ sub8) * 8;        // staging: logical granule for phys slot
    const int pg0 = ((quad)     ^ (lrow & 7)) * 8;    // ds_read: phys granule, ks=0
    const int pg1 = ((quad + 4) ^ (lrow & 7)) * 8;    // ks=1
    const int brow = (wn & 1) * 64;

    const int tileM = blockIdx.y * 256, tileN = blockIdx.x * 256;
    const int kslice = Kd / gridDim.z;
    const int kBeg = blockIdx.z * kslice;
    const int nt = kslice >> 6;

    const size_t thrOff = (size_t)(wave * 16 + sub8) * Kd + lgoff;
    const size_t c8 = (size_t)8 * Kd;                 // chunk1 = +8 rows
    const unsigned short* p0 = A + (size_t)tileM * Kd + kBeg + thrOff;          // A rows 0..127
    const unsigned short* p1 = p0 + (size_t)128 * Kd;                           // A rows 128..255
    const unsigned short* p2 = W + (size_t)tileN * Kd + kBeg + thrOff;          // B cols 0..127
    const unsigned short* p3 = p2 + (size_t)128 * Kd;                           // B cols 128..255

    const int ldst0 = wave * 1024 + lane * 8;         // chunk 2w   (ushort idx)
    const int ldst1 = ldst0 + 512;                    // chunk 2w+1

    floatx4 acc[8][4] = {};

    // prologue: stage K-tile 0 into buf 0 (8 async16 per thread)
    async16(&S[0][0][ldst0], p0); async16(&S[0][0][ldst1], p0 + c8);
    async16(&S[0][1][ldst0], p1); async16(&S[0][1][ldst1], p1 + c8);
    async16(&S[0][2][ldst0], p2); async16(&S[0][2][ldst1], p2 + c8);
    async16(&S[0][3][ldst0], p3); async16(&S[0][3][ldst1], p3 + c8);

    for (int tk = 0; tk < nt; ++tk) {
        const int cur = tk & 1, nxt = cur ^ 1;
        const size_t ko = (size_t)(tk + 1) * 64;
        const bool pf = (tk + 1 < nt);
        const unsigned short* Sa = &S[cur][wm][0];
        const unsigned short* Sb = &S[cur][2 + (wn >> 1)][0];

        if (pf) {   // issue next-tile A halves, then drain tile tk's 8 (keep 4 in flight)
            async16(&S[nxt][0][ldst0], p0 + ko);
            async16(&S[nxt][0][ldst1], p0 + ko + c8);
            async16(&S[nxt][1][ldst0], p1 + ko);
            async16(&S[nxt][1][ldst1], p1 + ko + c8);
            asm volatile("s_waitcnt vmcnt(4)" ::: "memory");
        } else {
            asm volatile("s_waitcnt vmcnt(0)" ::: "memory");
        }
        asm volatile("s_barrier" ::: "memory");   // B_ready: tile tk fully landed for all waves

        bf16x8 afr[4][2], bfr[4][2];
        // ---- phase 1: read A(mh0) + B(n0,n1); stage B halves of t+1; MFMA (m0-3)x(n0-1) ----
#pragma unroll
        for (int m = 0; m < 4; ++m) {
            const unsigned short* r = &Sa[(m * 16 + lrow) * 64];
            afr[m][0] = *(const bf16x8*)&r[pg0];
            afr[m][1] = *(const bf16x8*)&r[pg1];
        }
#pragma unroll
        for (int n = 0; n < 2; ++n) {
            const unsigned short* r = &Sb[(brow + n * 16 + lrow) * 64];
            bfr[n][0] = *(const bf16x8*)&r[pg0];
            bfr[n][1] = *(const bf16x8*)&r[pg1];
        }
        if (pf) {
            async16(&S[nxt][2][ldst0], p2 + ko);
            async16(&S[nxt][2][ldst1], p2 + ko + c8);
            async16(&S[nxt][3][ldst0], p3 + ko);
            async16(&S[nxt][3][ldst1], p3 + ko + c8);
        }
        asm volatile("s_barrier" ::: "memory");
        __builtin_amdgcn_s_setprio(1);
#pragma unroll
        for (int m = 0; m < 4; ++m)
#pragma unroll
            for (int n = 0; n < 2; ++n) {
                acc[m][n] = __builtin_amdgcn_mfma_f32_16x16x32_bf16(afr[m][0], bfr[n][0], acc[m][n], 0, 0, 0);
                acc[m][n] = __builtin_amdgcn_mfma_f32_16x16x32_bf16(afr[m][1], bfr[n][1], acc[m][n], 0, 0, 0);
            }
        __builtin_amdgcn_s_setprio(0);
        asm volatile("s_barrier" ::: "memory");

        // ---- phase 2: read B(n2,n3); MFMA (m0-3)x(n2-3) ----
#pragma unroll
        for (int n = 2; n < 4; ++n) {
            const unsigned short* r = &Sb[(brow + n * 16 + lrow) * 64];
            bfr[n][0] = *(const bf16x8*)&r[pg0];
            bfr[n][1] = *(const bf16x8*)&r[pg1];
        }
        asm volatile("s_barrier" ::: "memory");
        __builtin_amdgcn_s_setprio(1);
#pragma unroll
        for (int m = 0; m < 4; ++m)
#pragma unroll
            for (int n = 2; n < 4; ++n) {
                acc[m][n] = __builtin_amdgcn_mfma_f32_16x16x32_bf16(afr[m][0], bfr[n][0], acc[m][n], 0, 0, 0);
                acc[m][n] = __builtin_amdgcn_mfma_f32_16x16x32_bf16(afr[m][1], bfr[n][1], acc[m][n], 0, 0, 0);
            }
        __builtin_amdgcn_s_setprio(0);
        asm volatile("s_barrier" ::: "memory");

        // ---- phase 3: read A(mh1) (overwrite afr); MFMA (m4-7)x(n2-3) ----
#pragma unroll
        for (int m = 0; m < 4; ++m) {
            const unsigned short* r = &Sa[((m + 4) * 16 + lrow) * 64];
            afr[m][0] = *(const bf16x8*)&r[pg0];
            afr[m][1] = *(const bf16x8*)&r[pg1];
        }
        asm volatile("s_barrier" ::: "memory");
        __builtin_amdgcn_s_setprio(1);
#pragma unroll
        for (int m = 0; m < 4; ++m)
#pragma unroll
            for (int n = 2; n < 4; ++n) {
                acc[m + 4][n] = __builtin_amdgcn_mfma_f32_16x16x32_bf16(afr[m][0], bfr[n][0], acc[m + 4][n], 0, 0, 0);
                acc[m + 4][n] = __builtin_amdgcn_mfma_f32_16x16x32_bf16(afr[m][1], bfr[n][1], acc[m + 4][n], 0, 0, 0);
            }
        __builtin_amdgcn_s_setprio(0);
        asm volatile("s_barrier" ::: "memory");   // all LDS reads of buf[cur] complete chip-wide

        // ---- phase 4: registers only; MFMA (m4-7)x(n0-1) ----
        __builtin_amdgcn_s_setprio(1);
#pragma unroll
        for (int m = 0; m < 4; ++m)
#pragma unroll
            for (int n = 0; n < 2; ++n) {
                acc[m + 4][n] = __builtin_amdgcn_mfma_f32_16x16x32_bf16(afr[m][0], bfr[n][0], acc[m + 4][n], 0, 0, 0);
                acc[m + 4][n] = __builtin_amdgcn_mfma_f32_16x16x32_bf16(afr[m][1], bfr[n][1], acc[m + 4][n], 0, 0, 0);
            }
        __builtin_amdgcn_s_setprio(0);
    }

    // epilogue: C/D layout col=lane&15, row=quad*4+reg
#pragma unroll
    for (int m = 0; m < 8; ++m) {
        int gr0 = tileM + wm * 128 + m * 16 + quad * 4;
#pragma unroll
        for (int n = 0; n < 4; ++n) {
            int gc = tileN + wn * 64 + n * 16 + lrow;
#pragma unroll
            for (int r2 = 0; r2 < 4; ++r2) {
                size_t off = (size_t)(gr0 + r2) * Ncols + gc;
                if (OUTMODE == 0) ((unsigned short*)Cout)[off] = f2bf(acc[m][n][r2]);
                else              atomicAdd((float*)Cout + off, acc[m][n][r2]);
            }
        }
    }
}

// ---------------- RoPE + split qkv (bf16) -> q, k, vT (bf16) ----------------
__global__ __launch_bounds__(512) void rope_bf(
        const unsigned short* __restrict__ qkv, unsigned short* __restrict__ q,
        unsigned short* __restrict__ k, unsigned short* __restrict__ vt) {
    int n = blockIdx.x;
    int t = threadIdx.x;
    int h = t >> 5, j = t & 31;
    float inv = powf(10000.0f, -(float)j * (1.0f / 32.0f));
    float ang = (float)n * inv;
    float s = sinf(ang), c = cosf(ang);
    const unsigned short* base = qkv + (size_t)n * 3072;
    int o1 = h * 64 + j, o2 = o1 + 32;
    float q1 = bf2f(base[o1]),        q2 = bf2f(base[o2]);
    float k1 = bf2f(base[1024 + o1]), k2 = bf2f(base[1024 + o2]);
    q[(size_t)n * 1024 + o1] = f2bf(q1 * c - q2 * s);
    q[(size_t)n * 1024 + o2] = f2bf(q2 * c + q1 * s);
    k[(size_t)n * 1024 + o1] = f2bf(k1 * c - k2 * s);
    k[(size_t)n * 1024 + o2] = f2bf(k2 * c + k1 * s);
    vt[(size_t)o1 * 2048 + n] = base[2048 + o1];
    vt[(size_t)o2 * 2048 + n] = base[2048 + o2];
}

// ---------------- Flash attention (causal), bf16 in, bf16 out ----------------
// grid (32 qblocks, 16 heads), 256 thr = 4 waves; wave w owns q rows w*16..+15
__global__ __launch_bounds__(256) void attn_bf(
        const unsigned short* __restrict__ q, const unsigned short* __restrict__ kbuf,
        const unsigned short* __restrict__ vt, unsigned short* __restrict__ attn) {
    __shared__ __align__(16) unsigned short Qs[64 * 64];
    __shared__ __align__(16) unsigned short Ks[64 * 64];
    __shared__ __align__(16) unsigned short Vs[64 * 64];   // [dim][key]
    __shared__ __align__(16) unsigned short Ps[4 * 16 * 64];
    int qb = blockIdx.x;
    int h  = blockIdx.y;
    int t = threadIdx.x;
    int wave = t >> 6, lane = t & 63;
    int lrow = lane & 15, quad = lane >> 4;
    int sub8 = lane >> 3;           // row within 8-row chunk
    int col8 = (lane & 7) * 8;      // elem col within 64
    int c0 = wave, c1 = wave + 4;

    // stage Q (64 rows x 64 dims): 8 chunks of 1KB
    async16(&Qs[c0 * 512 + lane * 8], q + (size_t)(qb * 64 + c0 * 8 + sub8) * 1024 + h * 64 + col8);
    async16(&Qs[c1 * 512 + lane * 8], q + (size_t)(qb * 64 + c1 * 8 + sub8) * 1024 + h * 64 + col8);
    __syncthreads();   // Q landed (syncthreads drains vmcnt)
    // Q-hoist: this wave's Q fragment lives in regs for the whole KV loop
    bf16x8 aq0 = *(const bf16x8*)&Qs[(wave * 16 + lrow) * 64 + 0  + quad * 8];
    bf16x8 aq1 = *(const bf16x8*)&Qs[(wave * 16 + lrow) * 64 + 32 + quad * 8];

    floatx4 oacc[4] = {};
    float mrow[4], lsum[4];
#pragma unroll
    for (int r2 = 0; r2 < 4; r2++) { mrow[r2] = -INFINITY; lsum[r2] = 0.0f; }

    for (int kt = 0; kt <= qb; ++kt) {
        __syncthreads();  // prior iter's LDS reads done
        async16(&Ks[c0 * 512 + lane * 8], kbuf + (size_t)(kt * 64 + c0 * 8 + sub8) * 1024 + h * 64 + col8);
        async16(&Ks[c1 * 512 + lane * 8], kbuf + (size_t)(kt * 64 + c1 * 8 + sub8) * 1024 + h * 64 + col8);
        async16(&Vs[c0 * 512 + lane * 8], vt + (size_t)(h * 64 + c0 * 8 + sub8) * 2048 + kt * 64 + col8);
        async16(&Vs[c1 * 512 + lane * 8], vt + (size_t)(h * 64 + c1 * 8 + sub8) * 2048 + kt * 64 + col8);
        __syncthreads();

        // S = Q K^T (wave's 16 q rows x 64 keys)
        floatx4 sacc[4] = {};
#pragma unroll
        for (int jn = 0; jn < 4; jn++) {
            bf16x8 bk0 = *(const bf16x8*)&Ks[(jn * 16 + lrow) * 64 + 0  + quad * 8];
            bf16x8 bk1 = *(const bf16x8*)&Ks[(jn * 16 + lrow) * 64 + 32 + quad * 8];
            sacc[jn] = __builtin_amdgcn_mfma_f32_16x16x32_bf16(aq0, bk0, sacc[jn], 0, 0, 0);
            sacc[jn] = __builtin_amdgcn_mfma_f32_16x16x32_bf16(aq1, bk1, sacc[jn], 0, 0, 0);
        }

        const bool diag = (kt == qb);   // only the diagonal tile needs causal masking
        // online softmax per q-row (row = quad*4 + r2, 16 cols per 16-lane group)
#pragma unroll
        for (int r2 = 0; r2 < 4; r2++) {
            int qg = qb * 64 + wave * 16 + quad * 4 + r2;
            float sv[4];
            float rm = -INFINITY;
#pragma unroll
            for (int jn = 0; jn < 4; jn++) {
                float xv = sacc[jn][r2] * 0.125f;
                if (diag) {
                    int kg = kt * 64 + jn * 16 + lrow;
                    if (kg > qg) xv = -INFINITY;
                }
                sv[jn] = xv;
                rm = fmaxf(rm, xv);
            }
#pragma unroll
            for (int m = 8; m >= 1; m >>= 1) rm = fmaxf(rm, __shfl_xor(rm, m, 64));
            float mnew = fmaxf(mrow[r2], rm);
            float alpha = __expf(mrow[r2] - mnew);
            float rs = 0.0f;
#pragma unroll
            for (int jn = 0; jn < 4; jn++) {
                float p = __expf(sv[jn] - mnew);
                rs += p;
                Ps[wave * 1024 + (quad * 4 + r2) * 64 + jn * 16 + lrow] = f2bf(p);
            }
#pragma unroll
            for (int m = 8; m >= 1; m >>= 1) rs += __shfl_xor(rs, m, 64);
            lsum[r2] = lsum[r2] * alpha + rs;
            mrow[r2] = mnew;
#pragma unroll
            for (int jd = 0; jd < 4; jd++) oacc[jd][r2] *= alpha;
        }
        __syncthreads();  // Ps visible

        // O += P V
#pragma unroll
        for (int kk = 0; kk < 64; kk += 32) {
            bf16x8 ap = *(const bf16x8*)&Ps[wave * 1024 + lrow * 64 + kk + quad * 8];
#pragma unroll
            for (int jd = 0; jd < 4; jd++) {
                bf16x8 bv = *(const bf16x8*)&Vs[(jd * 16 + lrow) * 64 + kk + quad * 8];
                oacc[jd] = __builtin_amdgcn_mfma_f32_16x16x32_bf16(ap, bv, oacc[jd], 0, 0, 0);
            }
        }
    }

#pragma unroll
    for (int r2 = 0; r2 < 4; r2++) {
        int qg = qb * 64 + wave * 16 + quad * 4 + r2;
        float invl = 1.0f / lsum[r2];
#pragma unroll
        for (int jd = 0; jd < 4; jd++)
            attn[(size_t)qg * 1024 + h * 64 + jd * 16 + lrow] = f2bf(oacc[jd][r2] * invl);
    }
}

// ---------------- SiLU gate: a[2048,8192] bf16 -> g[2048,4096] bf16 ----------------
__global__ __launch_bounds__(256) void silu_bf(
        const unsigned short* __restrict__ a, unsigned short* __restrict__ g) {
    int i = blockIdx.x * 256 + threadIdx.x;   // ushort4 unit over 2048*4096
    int n = i >> 10, c = (i & 1023) << 2;
    ushort4 a1 = *(const ushort4*)(a + (size_t)n * 8192 + c);
    ushort4 a2 = *(const ushort4*)(a + (size_t)n * 8192 + 4096 + c);
    float x0 = bf2f(a1.x), x1 = bf2f(a1.y), x2 = bf2f(a1.z), x3 = bf2f(a1.w);
    ushort4 o;
    o.x = f2bf(x0 / (1.0f + __expf(-x0)) * bf2f(a2.x));
    o.y = f2bf(x1 / (1.0f + __expf(-x1)) * bf2f(a2.y));
    o.z = f2bf(x2 / (1.0f + __expf(-x2)) * bf2f(a2.z));
    o.w = f2bf(x3 / (1.0f + __expf(-x3)) * bf2f(a2.w));
    *(ushort4*)(g + (size_t)n * 4096 + c) = o;
}

// ---------------- launch ----------------
extern "C" void kernel_launch(void* const* d_in, const int* in_sizes, int n_in,
                              void* d_out, int out_size, void* d_ws, size_t ws_size,
                              hipStream_t stream) {
    const float* x     = (const float*)d_in[0];
    const float* qkv_w = (const float*)d_in[1];
    const float* out_w = (const float*)d_in[2];
    const float* w1    = (const float*)d_in[3];
    const float* w2    = (const float*)d_in[4];
    const float* n1    = (const float*)d_in[5];
    const float* n2    = (const float*)d_in[6];

    char* ws = (char*)d_ws;
    float*          xbuf  = (float*)ws;                                   // 8,388,608 B
    unsigned short* hbuf  = (unsigned short*)(ws + 8388608);              // 4,194,304 B
    unsigned short* wslot = (unsigned short*)(ws + 12582912);             // 33,554,432 B
    char*           arena = ws + 46137344;                                // 50,331,648 B
    unsigned short* qkvb  = (unsigned short*)arena;                       // 12,582,912 B
    unsigned short* qb_   = (unsigned short*)(arena + 12582912);          // 4,194,304 B
    unsigned short* kb_   = (unsigned short*)(arena + 16777216);
    unsigned short* vtb   = (unsigned short*)(arena + 20971520);
    unsigned short* attnb = (unsigned short*)(arena + 25165824);
    unsigned short* abuf  = (unsigned short*)arena;                       // 33,554,432 B (attn bufs dead)
    unsigned short* gbuf  = (unsigned short*)(arena + 33554432);          // 16,777,216 B

    unsigned short* qkvw_bf = wslot;
    unsigned short* outw_bf = wslot + 3145728;
    unsigned short* w1_bf   = wslot + 4194304;
    unsigned short* w2_bf   = wslot + 12582912;

    hipMemcpyAsync(xbuf, x, (size_t)2048 * 1024 * 4, hipMemcpyDeviceToDevice, stream);

    for (int i = 0; i < 6; i++) {
        conv_w<<<16384, 256, 0, stream>>>(qkv_w + (size_t)i * 3145728, out_w + (size_t)i * 1048576,
                                          w1 + (size_t)i * 8388608, w2 + (size_t)i * 4194304, wslot);
        rmsnorm_bf<<<2048, 256, 0, stream>>>(xbuf, n1 + (size_t)i * 1024, hbuf);
        gemm_bf<0><<<dim3(24, 16, 1), 256, 0, stream>>>(hbuf, qkvw_bf, qkvb, 3072, 1024);
        rope_bf<<<2048, 512, 0, stream>>>(qkvb, qb_, kb_, vtb);
        attn_bf<<<dim3(32, 16), 256, 0, stream>>>(qb_, kb_, vtb, attnb);
        gemm_bf<1><<<dim3(8, 16, 2), 256, 0, stream>>>(attnb, outw_bf, xbuf, 1024, 1024);
        rmsnorm_bf<<<2048, 256, 0, stream>>>(xbuf, n2 + (size_t)i * 1024, hbuf);
        gemm256<0><<<dim3(32, 8, 1), 512, 0, stream>>>(hbuf, w1_bf, abuf, 8192, 1024);
        silu_bf<<<8192, 256, 0, stream>>>(abuf, gbuf);
        gemm256<1><<<dim3(4, 8, 8), 512, 0, stream>>>(gbuf, w2_bf, xbuf, 1024, 4096);
    }

    hipMemcpyAsync(d_out, xbuf, (size_t)2048 * 1024 * 4, hipMemcpyDeviceToDevice, stream);
}

// Round 3
// 2066.784 us; speedup vs baseline: 1.0190x; 1.0060x over previous
//
#include <hip/hip_runtime.h>
#include <math.h>

typedef short bf16x8 __attribute__((ext_vector_type(8)));
typedef float floatx4 __attribute__((ext_vector_type(4)));

__device__ __forceinline__ unsigned short f2bf(float f) {
    unsigned int u = __float_as_uint(f);
    u += 0x7fffu + ((u >> 16) & 1u);   // round-to-nearest-even
    return (unsigned short)(u >> 16);
}
__device__ __forceinline__ float bf2f(unsigned short u) {
    return __uint_as_float(((unsigned int)u) << 16);
}
// async global->LDS, 16B per lane; LDS dest = wave-uniform base + lane*16
__device__ __forceinline__ void async16(void* lds, const void* g) {
    __builtin_amdgcn_global_load_lds((const __attribute__((address_space(1))) unsigned int*)g,
                                     (__attribute__((address_space(3))) unsigned int*)lds,
                                     16, 0, 0);
}
// XCD-aware bijective block swizzle (requires gridDim.x*gridDim.y % 8 == 0).
// Column-chunked: each XCD owns a contiguous x-range (B-panel set fits its L2).
__device__ __forceinline__ void xcd_swz(int& bx, int& by) {
    int nx = gridDim.x, ny = gridDim.y;
    int nwg = nx * ny;
    int bid = blockIdx.y * nx + blockIdx.x;
    int cpx = nwg >> 3;
    int swz = (bid & 7) * cpx + (bid >> 3);   // bijective when nwg%8==0
    bx = swz / ny; by = swz % ny;
}

// ---------------- weight convert: fp32 -> bf16, ALL 6 layers in one dispatch ----------------
// per-layer float4-unit segments: qkv 786432 | out 262144 | w1 2097152 | w2 1048576 (total 4194304)
__global__ __launch_bounds__(256) void conv_all(
        const float* __restrict__ qkv, const float* __restrict__ ow,
        const float* __restrict__ w1, const float* __restrict__ w2,
        unsigned short* __restrict__ dst) {
    int l = blockIdx.y;
    size_t i = (size_t)blockIdx.x * 256 + threadIdx.x;   // float4 unit within layer
    const float4* s; size_t off; unsigned short* d = dst + (size_t)l * 16777216;
    if (i < 786432)       { s = (const float4*)qkv + (size_t)l * 786432;  off = i; }
    else if (i < 1048576) { s = (const float4*)ow  + (size_t)l * 262144;  off = i - 786432;  d += 3145728; }
    else if (i < 3145728) { s = (const float4*)w1  + (size_t)l * 2097152; off = i - 1048576; d += 4194304; }
    else                  { s = (const float4*)w2  + (size_t)l * 1048576; off = i - 3145728; d += 12582912; }
    float4 v = s[off];
    ushort4 o;
    o.x = f2bf(v.x); o.y = f2bf(v.y); o.z = f2bf(v.z); o.w = f2bf(v.w);
    ((ushort4*)d)[off] = o;
}

// ---------------- RMSNorm: fp32 in -> bf16 out ----------------
__global__ __launch_bounds__(256) void rmsnorm_bf(
        const float* __restrict__ x, const float* __restrict__ w,
        unsigned short* __restrict__ out) {
    __shared__ float sred[4];
    int row = blockIdx.x;
    int t = threadIdx.x;
    float4 v = ((const float4*)(x + (size_t)row * 1024))[t];
    float ss = v.x*v.x + v.y*v.y + v.z*v.z + v.w*v.w;
#pragma unroll
    for (int m = 32; m >= 1; m >>= 1) ss += __shfl_xor(ss, m, 64);
    if ((t & 63) == 0) sred[t >> 6] = ss;
    __syncthreads();
    float tot = sred[0] + sred[1] + sred[2] + sred[3];
    float r = rsqrtf(tot * (1.0f / 1024.0f) + 1e-6f);
    float4 wv = ((const float4*)w)[t];
    ushort4 o;
    o.x = f2bf(v.x * r * wv.x); o.y = f2bf(v.y * r * wv.y);
    o.z = f2bf(v.z * r * wv.z); o.w = f2bf(v.w * r * wv.w);
    ((ushort4*)(out + (size_t)row * 1024))[t] = o;
}

// ---------------- GEMM: C[M,Nc] = A[M,Kd] * W[Nc,Kd]^T, bf16 in ----------------
// 128x128 tile, BK=32, 256 thr = 4 waves (2x2 of 64x64), m97 structure + XCD swizzle.
// OUTMODE 0: store bf16. OUTMODE 1: fp32 atomicAdd (split-K over blockIdx.z; residual free).
template<int OUTMODE>
__global__ __launch_bounds__(256) void gemm_bf(
        const unsigned short* __restrict__ A, const unsigned short* __restrict__ W,
        void* __restrict__ Cout, int Ncols, int Kd) {
    __shared__ __align__(16) unsigned short As[128 * 32];
    __shared__ __align__(16) unsigned short Bs[128 * 32];
    int t = threadIdx.x;
    int wave = t >> 6, lane = t & 63;
    int wm = wave >> 1, wn = wave & 1;
    int lrow = lane & 15, quad = lane >> 4;
    int bx, by; xcd_swz(bx, by);
    int bmBase = by * 128, bnBase = bx * 128;
    int kslice = Kd / gridDim.z;
    int kBeg = blockIdx.z * kslice, kEnd = kBeg + kslice;

    int sub = lane >> 2;           // row within chunk (16 rows of 64B)
    int colb = (lane & 3) * 8;     // elem col within 32
    int c0 = wave, c1 = wave + 4;  // this wave's chunks (of 8 per tile)

    floatx4 acc[4][4] = {};

    for (int k0 = kBeg; k0 < kEnd; k0 += 32) {
        async16(&As[c0 * 512 + lane * 8], A + (size_t)(bmBase + c0 * 16 + sub) * Kd + k0 + colb);
        async16(&As[c1 * 512 + lane * 8], A + (size_t)(bmBase + c1 * 16 + sub) * Kd + k0 + colb);
        async16(&Bs[c0 * 512 + lane * 8], W + (size_t)(bnBase + c0 * 16 + sub) * Kd + k0 + colb);
        async16(&Bs[c1 * 512 + lane * 8], W + (size_t)(bnBase + c1 * 16 + sub) * Kd + k0 + colb);
        __syncthreads();
        bf16x8 af[4], bfr[4];
#pragma unroll
        for (int im = 0; im < 4; im++)
            af[im] = *(const bf16x8*)&As[(wm * 64 + im * 16 + lrow) * 32 + quad * 8];
#pragma unroll
        for (int in = 0; in < 4; in++)
            bfr[in] = *(const bf16x8*)&Bs[(wn * 64 + in * 16 + lrow) * 32 + quad * 8];
#pragma unroll
        for (int im = 0; im < 4; im++)
#pragma unroll
            for (int in = 0; in < 4; in++)
                acc[im][in] = __builtin_amdgcn_mfma_f32_16x16x32_bf16(af[im], bfr[in], acc[im][in], 0, 0, 0);
        __syncthreads();
    }

#pragma unroll
    for (int im = 0; im < 4; im++) {
        int gr0 = bmBase + wm * 64 + im * 16 + quad * 4;
#pragma unroll
        for (int in = 0; in < 4; in++) {
            int gc = bnBase + wn * 64 + in * 16 + lrow;
#pragma unroll
            for (int r2 = 0; r2 < 4; r2++) {
                size_t off = (size_t)(gr0 + r2) * Ncols + gc;
                if (OUTMODE == 0) ((unsigned short*)Cout)[off] = f2bf(acc[im][in][r2]);
                else              atomicAdd((float*)Cout + off, acc[im][in][r2]);
            }
        }
    }
}

// ---------------- Fused W1 + SiLU gate: G[2048,4096] = silu(A*W1a^T) . (A*W1b^T) ----------------
// W = w1_bf [8192,1024]; W1a = rows [0,4096), W1b = rows [4096,8192).
// 128x128 output tile of G, both gemms in one block (A staged once, 2 B panels).
__global__ __launch_bounds__(256, 2) void gemm_gate(
        const unsigned short* __restrict__ A, const unsigned short* __restrict__ W,
        unsigned short* __restrict__ G) {
    __shared__ __align__(16) unsigned short As[128 * 32];
    __shared__ __align__(16) unsigned short B1s[128 * 32];
    __shared__ __align__(16) unsigned short B2s[128 * 32];
    int t = threadIdx.x;
    int wave = t >> 6, lane = t & 63;
    int wm = wave >> 1, wn = wave & 1;
    int lrow = lane & 15, quad = lane >> 4;
    int bx, by; xcd_swz(bx, by);
    int bmBase = by * 128, bnBase = bx * 128;
    const int Kd = 1024;

    int sub = lane >> 2;
    int colb = (lane & 3) * 8;
    int c0 = wave, c1 = wave + 4;

    floatx4 acc1[4][4] = {}, acc2[4][4] = {};

    for (int k0 = 0; k0 < 1024; k0 += 32) {
        async16(&As[c0 * 512 + lane * 8],  A + (size_t)(bmBase + c0 * 16 + sub) * Kd + k0 + colb);
        async16(&As[c1 * 512 + lane * 8],  A + (size_t)(bmBase + c1 * 16 + sub) * Kd + k0 + colb);
        async16(&B1s[c0 * 512 + lane * 8], W + (size_t)(bnBase + c0 * 16 + sub) * Kd + k0 + colb);
        async16(&B1s[c1 * 512 + lane * 8], W + (size_t)(bnBase + c1 * 16 + sub) * Kd + k0 + colb);
        async16(&B2s[c0 * 512 + lane * 8], W + (size_t)(4096 + bnBase + c0 * 16 + sub) * Kd + k0 + colb);
        async16(&B2s[c1 * 512 + lane * 8], W + (size_t)(4096 + bnBase + c1 * 16 + sub) * Kd + k0 + colb);
        __syncthreads();
        bf16x8 af[4], b1[4], b2[4];
#pragma unroll
        for (int im = 0; im < 4; im++)
            af[im] = *(const bf16x8*)&As[(wm * 64 + im * 16 + lrow) * 32 + quad * 8];
#pragma unroll
        for (int in = 0; in < 4; in++) {
            b1[in] = *(const bf16x8*)&B1s[(wn * 64 + in * 16 + lrow) * 32 + quad * 8];
            b2[in] = *(const bf16x8*)&B2s[(wn * 64 + in * 16 + lrow) * 32 + quad * 8];
        }
#pragma unroll
        for (int im = 0; im < 4; im++)
#pragma unroll
            for (int in = 0; in < 4; in++) {
                acc1[im][in] = __builtin_amdgcn_mfma_f32_16x16x32_bf16(af[im], b1[in], acc1[im][in], 0, 0, 0);
                acc2[im][in] = __builtin_amdgcn_mfma_f32_16x16x32_bf16(af[im], b2[in], acc2[im][in], 0, 0, 0);
            }
        __syncthreads();
    }

#pragma unroll
    for (int im = 0; im < 4; im++) {
        int gr0 = bmBase + wm * 64 + im * 16 + quad * 4;
#pragma unroll
        for (int in = 0; in < 4; in++) {
            int gc = bnBase + wn * 64 + in * 16 + lrow;
#pragma unroll
            for (int r2 = 0; r2 < 4; r2++) {
                float v1 = acc1[im][in][r2], v2 = acc2[im][in][r2];
                G[(size_t)(gr0 + r2) * 4096 + gc] = f2bf(v1 / (1.0f + __expf(-v1)) * v2);
            }
        }
    }
}

// ---------------- RoPE + split qkv (bf16) -> q, k, vT (bf16) ----------------
__global__ __launch_bounds__(512) void rope_bf(
        const unsigned short* __restrict__ qkv, unsigned short* __restrict__ q,
        unsigned short* __restrict__ k, unsigned short* __restrict__ vt) {
    int n = blockIdx.x;
    int t = threadIdx.x;
    int h = t >> 5, j = t & 31;
    float inv = exp2f((float)j * -0.4152410118609203f);   // 10000^(-j/32), log2(1e4)/32
    float ang = (float)n * inv;
    float s = sinf(ang), c = cosf(ang);
    const unsigned short* base = qkv + (size_t)n * 3072;
    int o1 = h * 64 + j, o2 = o1 + 32;
    float q1 = bf2f(base[o1]),        q2 = bf2f(base[o2]);
    float k1 = bf2f(base[1024 + o1]), k2 = bf2f(base[1024 + o2]);
    q[(size_t)n * 1024 + o1] = f2bf(q1 * c - q2 * s);
    q[(size_t)n * 1024 + o2] = f2bf(q2 * c + q1 * s);
    k[(size_t)n * 1024 + o1] = f2bf(k1 * c - k2 * s);
    k[(size_t)n * 1024 + o2] = f2bf(k2 * c + k1 * s);
    vt[(size_t)o1 * 2048 + n] = base[2048 + o1];
    vt[(size_t)o2 * 2048 + n] = base[2048 + o2];
}

// ---------------- Flash attention (causal), bf16 in, bf16 out ----------------
// grid (32 qblocks, 16 heads), 256 thr = 4 waves; wave w owns q rows w*16..+15
__global__ __launch_bounds__(256) void attn_bf(
        const unsigned short* __restrict__ q, const unsigned short* __restrict__ kbuf,
        const unsigned short* __restrict__ vt, unsigned short* __restrict__ attn) {
    __shared__ __align__(16) unsigned short Qs[64 * 64];
    __shared__ __align__(16) unsigned short Ks[64 * 64];
    __shared__ __align__(16) unsigned short Vs[64 * 64];   // [dim][key]
    __shared__ __align__(16) unsigned short Ps[4 * 16 * 64];
    int qb = blockIdx.x;
    int h  = blockIdx.y;
    int t = threadIdx.x;
    int wave = t >> 6, lane = t & 63;
    int lrow = lane & 15, quad = lane >> 4;
    int sub8 = lane >> 3;           // row within 8-row chunk
    int col8 = (lane & 7) * 8;      // elem col within 64
    int c0 = wave, c1 = wave + 4;

    // stage Q (64 rows x 64 dims): 8 chunks of 1KB
    async16(&Qs[c0 * 512 + lane * 8], q + (size_t)(qb * 64 + c0 * 8 + sub8) * 1024 + h * 64 + col8);
    async16(&Qs[c1 * 512 + lane * 8], q + (size_t)(qb * 64 + c1 * 8 + sub8) * 1024 + h * 64 + col8);
    __syncthreads();   // Q landed (syncthreads drains vmcnt)
    // Q-hoist: this wave's Q fragment lives in regs for the whole KV loop
    bf16x8 aq0 = *(const bf16x8*)&Qs[(wave * 16 + lrow) * 64 + 0  + quad * 8];
    bf16x8 aq1 = *(const bf16x8*)&Qs[(wave * 16 + lrow) * 64 + 32 + quad * 8];

    floatx4 oacc[4] = {};
    float mrow[4], lsum[4];
#pragma unroll
    for (int r2 = 0; r2 < 4; r2++) { mrow[r2] = -INFINITY; lsum[r2] = 0.0f; }

    for (int kt = 0; kt <= qb; ++kt) {
        __syncthreads();  // prior iter's LDS reads done
        async16(&Ks[c0 * 512 + lane * 8], kbuf + (size_t)(kt * 64 + c0 * 8 + sub8) * 1024 + h * 64 + col8);
        async16(&Ks[c1 * 512 + lane * 8], kbuf + (size_t)(kt * 64 + c1 * 8 + sub8) * 1024 + h * 64 + col8);
        async16(&Vs[c0 * 512 + lane * 8], vt + (size_t)(h * 64 + c0 * 8 + sub8) * 2048 + kt * 64 + col8);
        async16(&Vs[c1 * 512 + lane * 8], vt + (size_t)(h * 64 + c1 * 8 + sub8) * 2048 + kt * 64 + col8);
        __syncthreads();

        // S = Q K^T (wave's 16 q rows x 64 keys)
        floatx4 sacc[4] = {};
#pragma unroll
        for (int jn = 0; jn < 4; jn++) {
            bf16x8 bk0 = *(const bf16x8*)&Ks[(jn * 16 + lrow) * 64 + 0  + quad * 8];
            bf16x8 bk1 = *(const bf16x8*)&Ks[(jn * 16 + lrow) * 64 + 32 + quad * 8];
            sacc[jn] = __builtin_amdgcn_mfma_f32_16x16x32_bf16(aq0, bk0, sacc[jn], 0, 0, 0);
            sacc[jn] = __builtin_amdgcn_mfma_f32_16x16x32_bf16(aq1, bk1, sacc[jn], 0, 0, 0);
        }

        const bool diag = (kt == qb);   // only the diagonal tile needs causal masking
        // online softmax per q-row (row = quad*4 + r2, 16 cols per 16-lane group)
#pragma unroll
        for (int r2 = 0; r2 < 4; r2++) {
            int qg = qb * 64 + wave * 16 + quad * 4 + r2;
            float sv[4];
            float rm = -INFINITY;
#pragma unroll
            for (int jn = 0; jn < 4; jn++) {
                float xv = sacc[jn][r2] * 0.125f;
                if (diag) {
                    int kg = kt * 64 + jn * 16 + lrow;
                    if (kg > qg) xv = -INFINITY;
                }
                sv[jn] = xv;
                rm = fmaxf(rm, xv);
            }
#pragma unroll
            for (int m = 8; m >= 1; m >>= 1) rm = fmaxf(rm, __shfl_xor(rm, m, 64));
            float mnew = fmaxf(mrow[r2], rm);
            float alpha = __expf(mrow[r2] - mnew);
            float rs = 0.0f;
#pragma unroll
            for (int jn = 0; jn < 4; jn++) {
                float p = __expf(sv[jn] - mnew);
                rs += p;
                Ps[wave * 1024 + (quad * 4 + r2) * 64 + jn * 16 + lrow] = f2bf(p);
            }
#pragma unroll
            for (int m = 8; m >= 1; m >>= 1) rs += __shfl_xor(rs, m, 64);
            lsum[r2] = lsum[r2] * alpha + rs;
            mrow[r2] = mnew;
#pragma unroll
            for (int jd = 0; jd < 4; jd++) oacc[jd][r2] *= alpha;
        }
        __syncthreads();  // Ps visible

        // O += P V
#pragma unroll
        for (int kk = 0; kk < 64; kk += 32) {
            bf16x8 ap = *(const bf16x8*)&Ps[wave * 1024 + lrow * 64 + kk + quad * 8];
#pragma unroll
            for (int jd = 0; jd < 4; jd++) {
                bf16x8 bv = *(const bf16x8*)&Vs[(jd * 16 + lrow) * 64 + kk + quad * 8];
                oacc[jd] = __builtin_amdgcn_mfma_f32_16x16x32_bf16(ap, bv, oacc[jd], 0, 0, 0);
            }
        }
    }

#pragma unroll
    for (int r2 = 0; r2 < 4; r2++) {
        int qg = qb * 64 + wave * 16 + quad * 4 + r2;
        float invl = 1.0f / lsum[r2];
#pragma unroll
        for (int jd = 0; jd < 4; jd++)
            attn[(size_t)qg * 1024 + h * 64 + jd * 16 + lrow] = f2bf(oacc[jd][r2] * invl);
    }
}

// ---------------- launch ----------------
extern "C" void kernel_launch(void* const* d_in, const int* in_sizes, int n_in,
                              void* d_out, int out_size, void* d_ws, size_t ws_size,
                              hipStream_t stream) {
    const float* x     = (const float*)d_in[0];
    const float* qkv_w = (const float*)d_in[1];
    const float* out_w = (const float*)d_in[2];
    const float* w1    = (const float*)d_in[3];
    const float* w2    = (const float*)d_in[4];
    const float* n1    = (const float*)d_in[5];
    const float* n2    = (const float*)d_in[6];

    char* ws = (char*)d_ws;
    float*          xbuf  = (float*)ws;                                   // 8,388,608 B
    unsigned short* hbuf  = (unsigned short*)(ws + 8388608);              // 4,194,304 B
    unsigned short* wall  = (unsigned short*)(ws + 12582912);             // 201,326,592 B (6 layers bf16)
    char*           arena = ws + 213909504;                               // ~29.4 MB live
    unsigned short* qkvb  = (unsigned short*)arena;                       // 12,582,912 B
    unsigned short* qb_   = (unsigned short*)(arena + 12582912);          // 4,194,304 B
    unsigned short* kb_   = (unsigned short*)(arena + 16777216);
    unsigned short* vtb   = (unsigned short*)(arena + 20971520);
    unsigned short* attnb = (unsigned short*)(arena + 25165824);
    unsigned short* gbuf  = (unsigned short*)arena;                       // 16,777,216 B (overlays dead qkv/q bufs)

    hipMemcpyAsync(xbuf, x, (size_t)2048 * 1024 * 4, hipMemcpyDeviceToDevice, stream);

    // convert all 6 layers' weights once, upfront
    conv_all<<<dim3(16384, 6), 256, 0, stream>>>(qkv_w, out_w, w1, w2, wall);

    for (int i = 0; i < 6; i++) {
        unsigned short* wl      = wall + (size_t)i * 16777216;
        unsigned short* qkvw_bf = wl;
        unsigned short* outw_bf = wl + 3145728;
        unsigned short* w1_bf   = wl + 4194304;
        unsigned short* w2_bf   = wl + 12582912;

        rmsnorm_bf<<<2048, 256, 0, stream>>>(xbuf, n1 + (size_t)i * 1024, hbuf);
        gemm_bf<0><<<dim3(24, 16, 1), 256, 0, stream>>>(hbuf, qkvw_bf, qkvb, 3072, 1024);
        rope_bf<<<2048, 512, 0, stream>>>(qkvb, qb_, kb_, vtb);
        attn_bf<<<dim3(32, 16), 256, 0, stream>>>(qb_, kb_, vtb, attnb);
        gemm_bf<1><<<dim3(8, 16, 2), 256, 0, stream>>>(attnb, outw_bf, xbuf, 1024, 1024);
        rmsnorm_bf<<<2048, 256, 0, stream>>>(xbuf, n2 + (size_t)i * 1024, hbuf);
        gemm_gate<<<dim3(32, 16), 256, 0, stream>>>(hbuf, w1_bf, gbuf);
        gemm_bf<1><<<dim3(8, 16, 4), 256, 0, stream>>>(gbuf, w2_bf, xbuf, 1024, 4096);
    }

    hipMemcpyAsync(d_out, xbuf, (size_t)2048 * 1024 * 4, hipMemcpyDeviceToDevice, stream);
}